// Round 7
// baseline (171.825 us; speedup 1.0000x reference)
//
#include <hip/hip_runtime.h>

#define NB 32
#define DIM 64
#define BSHIFT 6          // bucket = 64 node rows = 8 KB fp16 window
#define MAXBUCK 1024
#define SEPB 8            // edges per thread in scatter

typedef _Float16 half8_t __attribute__((ext_vector_type(8)));
typedef float floatx4 __attribute__((ext_vector_type(4)));
typedef int int2v __attribute__((ext_vector_type(2)));

// ---------------- prep: convert Eu/Ev/E_b (f32) -> fp16 tables in ws -------
__global__ __launch_bounds__(256) void cvt_f16_kernel(
    const float* __restrict__ Eu, const float* __restrict__ Ev,
    const float* __restrict__ E_b,
    _Float16* __restrict__ EuH, _Float16* __restrict__ EvH,
    _Float16* __restrict__ EbH, int n8)
{
    int i = blockIdx.x * blockDim.x + threadIdx.x;
    if (i < n8) {
        const float4* u4 = (const float4*)Eu + 2 * i;
        const float4* v4 = (const float4*)Ev + 2 * i;
        float4 a0 = u4[0], a1 = u4[1];
        float4 b0 = v4[0], b1 = v4[1];
        half8_t hu, hv;
        hu[0] = (_Float16)a0.x; hu[1] = (_Float16)a0.y; hu[2] = (_Float16)a0.z; hu[3] = (_Float16)a0.w;
        hu[4] = (_Float16)a1.x; hu[5] = (_Float16)a1.y; hu[6] = (_Float16)a1.z; hu[7] = (_Float16)a1.w;
        hv[0] = (_Float16)b0.x; hv[1] = (_Float16)b0.y; hv[2] = (_Float16)b0.z; hv[3] = (_Float16)b0.w;
        hv[4] = (_Float16)b1.x; hv[5] = (_Float16)b1.y; hv[6] = (_Float16)b1.z; hv[7] = (_Float16)b1.w;
        ((half8_t*)EuH)[i] = hu;
        ((half8_t*)EvH)[i] = hv;
    }
    if (blockIdx.x == 0) {
        int base = threadIdx.x * 8;
        if (base < NB * DIM) {
            const float4* b4 = (const float4*)(E_b + base);
            float4 x0 = b4[0], x1 = b4[1];
            half8_t h;
            h[0] = (_Float16)x0.x; h[1] = (_Float16)x0.y; h[2] = (_Float16)x0.z; h[3] = (_Float16)x0.w;
            h[4] = (_Float16)x1.x; h[5] = (_Float16)x1.y; h[6] = (_Float16)x1.z; h[7] = (_Float16)x1.w;
            *(half8_t*)(EbH + base) = h;
        }
    }
}

// ---------------- sort pass 1: bucket histogram ----------------------------
__global__ __launch_bounds__(256) void hist_kernel(
    const int* __restrict__ edge_index, int E, int nbuck,
    unsigned* __restrict__ ghist)
{
    __shared__ unsigned h[MAXBUCK];
    for (int i = threadIdx.x; i < nbuck; i += blockDim.x) h[i] = 0u;
    __syncthreads();
    for (int e = blockIdx.x * blockDim.x + threadIdx.x; e < E;
         e += gridDim.x * blockDim.x) {
        int s = __builtin_nontemporal_load(edge_index + e);
        atomicAdd(&h[s >> BSHIFT], 1u);
    }
    __syncthreads();
    for (int i = threadIdx.x; i < nbuck; i += blockDim.x)
        if (h[i]) atomicAdd(&ghist[i], h[i]);
}

// ---------------- sort pass 2: exclusive scan -> base & cursor -------------
__global__ __launch_bounds__(1024) void scan_kernel(
    const unsigned* __restrict__ ghist, int nbuck,
    unsigned* __restrict__ cursor)
{
    __shared__ unsigned a[MAXBUCK], b[MAXBUCK];
    int t = threadIdx.x;
    unsigned own = (t < nbuck) ? ghist[t] : 0u;
    a[t] = own;
    __syncthreads();
    unsigned* pin = a; unsigned* pout = b;
    for (int off = 1; off < MAXBUCK; off <<= 1) {
        unsigned x = pin[t] + ((t >= off) ? pin[t - off] : 0u);
        pout[t] = x;
        __syncthreads();
        unsigned* tmp = pin; pin = pout; pout = tmp;
    }
    if (t < nbuck) cursor[t] = pin[t] - own;   // exclusive prefix
}

// ---------------- sort pass 3: two-level scatter ---------------------------
__global__ __launch_bounds__(512) void scatter_kernel(
    const int* __restrict__ edge_index, int E, int nbuck,
    unsigned* __restrict__ cursor,
    int2v* __restrict__ sSD, int* __restrict__ sId)
{
    __shared__ unsigned lcnt[MAXBUCK];
    __shared__ unsigned lbase[MAXBUCK];
    for (int i = threadIdx.x; i < nbuck; i += 512) lcnt[i] = 0u;
    __syncthreads();

    int e0 = blockIdx.x * (512 * SEPB);
    int src_[SEPB], dst_[SEPB];
#pragma unroll
    for (int k = 0; k < SEPB; ++k) {
        int e = e0 + k * 512 + threadIdx.x;
        if (e < E) {
            src_[k] = __builtin_nontemporal_load(edge_index + e);
            dst_[k] = __builtin_nontemporal_load(edge_index + E + e);
            atomicAdd(&lcnt[src_[k] >> BSHIFT], 1u);
        }
    }
    __syncthreads();
    for (int i = threadIdx.x; i < nbuck; i += 512) {
        unsigned c = lcnt[i];
        lbase[i] = c ? atomicAdd(&cursor[i], c) : 0u;
    }
    __syncthreads();
    for (int i = threadIdx.x; i < nbuck; i += 512) lcnt[i] = 0u;
    __syncthreads();
#pragma unroll
    for (int k = 0; k < SEPB; ++k) {
        int e = e0 + k * 512 + threadIdx.x;
        if (e < E) {
            int bk = src_[k] >> BSHIFT;
            unsigned r = atomicAdd(&lcnt[bk], 1u);
            unsigned pos = lbase[bk] + r;
            int2v p; p.x = src_[k]; p.y = dst_[k];
            sSD[pos] = p;
            sId[pos] = e;
        }
    }
}

// ---------------- main: per-wave 64 sorted edges, logits transposed --------
// acc = mfma(A = E_b rows, B = r^T):
//   D-frag: col = lane&15 = edge, row = (lane>>4)*4 + reg = b (within mt tile)
// Sorted-by-src-bucket => u-gathers hit an 8 KB window (L1-hot); v random.
// Issue v (long latency) before u (short).
__global__ __launch_bounds__(256, 4) void ptt_mfma_sorted_kernel(
    const _Float16* __restrict__ EuH, const _Float16* __restrict__ EvH,
    const int2v* __restrict__ sSD, const int* __restrict__ sId,
    const _Float16* __restrict__ EbH,
    float* __restrict__ out, int E)
{
    const int lane = threadIdx.x & 63;
    const int wave = threadIdx.x >> 6;
    const int j16 = lane & 15;
    const int g = lane >> 4;
    const int eb = (blockIdx.x * 4 + wave) * 64;

    int2v sd[4]; int iid[4];
#pragma unroll
    for (int t = 0; t < 4; ++t) {
        int e = eb + t * 16 + j16;
        int ec = e < E ? e : (E - 1);
        sd[t] = __builtin_nontemporal_load(sSD + ec);
        iid[t] = __builtin_nontemporal_load(sId + ec);
    }

    half8_t Af[2][2];
#pragma unroll
    for (int mt = 0; mt < 2; ++mt)
#pragma unroll
        for (int ks = 0; ks < 2; ++ks)
            Af[mt][ks] = *(const half8_t*)(EbH + (mt * 16 + j16) * DIM + ks * 32 + g * 8);

    const char* ub = (const char*)EuH;
    const char* vb = (const char*)EvH;
    half8_t u[4][2], v[4][2];
#pragma unroll
    for (int t = 0; t < 4; ++t) {
        unsigned sv = (unsigned)sd[t].y * (DIM * 2u) + (unsigned)(g * 16);
#pragma unroll
        for (int ks = 0; ks < 2; ++ks)
            v[t][ks] = *(const half8_t*)(vb + (sv + ks * 64u));
    }
#pragma unroll
    for (int t = 0; t < 4; ++t) {
        unsigned su = (unsigned)sd[t].x * (DIM * 2u) + (unsigned)(g * 16);
#pragma unroll
        for (int ks = 0; ks < 2; ++ks)
            u[t][ks] = *(const half8_t*)(ub + (su + ks * 64u));
    }

    floatx4 acc[4][2];
#pragma unroll
    for (int t = 0; t < 4; ++t) {
        acc[t][0] = (floatx4){0.f, 0.f, 0.f, 0.f};
        acc[t][1] = (floatx4){0.f, 0.f, 0.f, 0.f};
    }

#pragma unroll
    for (int t = 0; t < 4; ++t)
#pragma unroll
        for (int ks = 0; ks < 2; ++ks) {
            half8_t r = u[t][ks] * v[t][ks];  // v_pk_mul_f16
            acc[t][0] = __builtin_amdgcn_mfma_f32_16x16x32_f16(Af[0][ks], r, acc[t][0], 0, 0, 0);
            acc[t][1] = __builtin_amdgcn_mfma_f32_16x16x32_f16(Af[1][ks], r, acc[t][1], 0, 0, 0);
        }

    // Epilogue: softmax-weighted logit mean + sigmoid (no max-sub: |logit|<~8).
#pragma unroll
    for (int t = 0; t < 4; ++t) {
        float s1 = 0.f, s2 = 0.f;
#pragma unroll
        for (int mt = 0; mt < 2; ++mt)
#pragma unroll
            for (int q = 0; q < 4; ++q) {
                float a = acc[t][mt][q];
                float p = __expf(a);
                s1 += p;
                s2 = fmaf(p, a, s2);
            }
        s1 += __shfl_xor(s1, 16);
        s2 += __shfl_xor(s2, 16);
        s1 += __shfl_xor(s1, 32);
        s2 += __shfl_xor(s2, 32);
        float x = __fdividef(s2, s1);
        float score = __fdividef(1.0f, 1.0f + __expf(-x));
        if (lane < 16) {
            int eo = eb + t * 16 + j16;
            if (eo < E) __builtin_nontemporal_store(score, out + iid[t]);
        }
    }
}

// ---------------- unsorted fp16 path (ws too small for sort) ---------------
__global__ __launch_bounds__(256, 4) void ptt_mfma_kernel(
    const _Float16* __restrict__ EuH, const _Float16* __restrict__ EvH,
    const int* __restrict__ edge_index,
    const _Float16* __restrict__ EbH,
    float* __restrict__ out, int E)
{
    const int lane = threadIdx.x & 63;
    const int wave = threadIdx.x >> 6;
    const int j16 = lane & 15;
    const int g = lane >> 4;
    const int eb = (blockIdx.x * 4 + wave) * 64;

    int isrc[4], idst[4];
#pragma unroll
    for (int t = 0; t < 4; ++t) {
        int e = eb + t * 16 + j16;
        int ec = e < E ? e : (E - 1);
        isrc[t] = __builtin_nontemporal_load(edge_index + ec);
        idst[t] = __builtin_nontemporal_load(edge_index + E + ec);
    }

    half8_t Af[2][2];
#pragma unroll
    for (int mt = 0; mt < 2; ++mt)
#pragma unroll
        for (int ks = 0; ks < 2; ++ks)
            Af[mt][ks] = *(const half8_t*)(EbH + (mt * 16 + j16) * DIM + ks * 32 + g * 8);

    const char* ub = (const char*)EuH;
    const char* vb = (const char*)EvH;
    half8_t u[4][2], v[4][2];
#pragma unroll
    for (int t = 0; t < 4; ++t) {
        unsigned su = (unsigned)isrc[t] * (DIM * 2u) + (unsigned)(g * 16);
        unsigned sv = (unsigned)idst[t] * (DIM * 2u) + (unsigned)(g * 16);
#pragma unroll
        for (int ks = 0; ks < 2; ++ks) {
            u[t][ks] = *(const half8_t*)(ub + (su + ks * 64u));
            v[t][ks] = *(const half8_t*)(vb + (sv + ks * 64u));
        }
    }

    floatx4 acc[4][2];
#pragma unroll
    for (int t = 0; t < 4; ++t) {
        acc[t][0] = (floatx4){0.f, 0.f, 0.f, 0.f};
        acc[t][1] = (floatx4){0.f, 0.f, 0.f, 0.f};
    }

#pragma unroll
    for (int t = 0; t < 4; ++t)
#pragma unroll
        for (int ks = 0; ks < 2; ++ks) {
            half8_t r = u[t][ks] * v[t][ks];
            acc[t][0] = __builtin_amdgcn_mfma_f32_16x16x32_f16(Af[0][ks], r, acc[t][0], 0, 0, 0);
            acc[t][1] = __builtin_amdgcn_mfma_f32_16x16x32_f16(Af[1][ks], r, acc[t][1], 0, 0, 0);
        }

#pragma unroll
    for (int t = 0; t < 4; ++t) {
        float s1 = 0.f, s2 = 0.f;
#pragma unroll
        for (int mt = 0; mt < 2; ++mt)
#pragma unroll
            for (int q = 0; q < 4; ++q) {
                float a = acc[t][mt][q];
                float p = __expf(a);
                s1 += p;
                s2 = fmaf(p, a, s2);
            }
        s1 += __shfl_xor(s1, 16);
        s2 += __shfl_xor(s2, 16);
        s1 += __shfl_xor(s1, 32);
        s2 += __shfl_xor(s2, 32);
        float x = __fdividef(s2, s1);
        float score = __fdividef(1.0f, 1.0f + __expf(-x));
        if (lane < 16) {
            int eo = eb + t * 16 + j16;
            if (eo < E) __builtin_nontemporal_store(score, out + eo);
        }
    }
}

static inline size_t align256(size_t x) { return (x + 255) & ~(size_t)255; }

extern "C" void kernel_launch(void* const* d_in, const int* in_sizes, int n_in,
                              void* d_out, int out_size, void* d_ws, size_t ws_size,
                              hipStream_t stream) {
    const float* Eu = (const float*)d_in[0];
    const float* Ev = (const float*)d_in[1];
    const int* edge_index = (const int*)d_in[2];  // harness delivers int32
    const float* E_b = (const float*)d_in[3];
    float* out = (float*)d_out;

    int n_nodes_elems = in_sizes[0];          // 50000*64
    int n_nodes = n_nodes_elems / DIM;
    int E = in_sizes[2] / 2;
    int nbuck = (n_nodes + (1 << BSHIFT) - 1) >> BSHIFT;

    // ws layout
    size_t off = 0;
    size_t o_EuH = off; off = align256(off + (size_t)n_nodes_elems * 2);
    size_t o_EvH = off; off = align256(off + (size_t)n_nodes_elems * 2);
    size_t o_EbH = off; off = align256(off + (size_t)NB * DIM * 2);
    size_t o_hist = off; off = align256(off + (size_t)MAXBUCK * 4);
    size_t o_cur  = off; off = align256(off + (size_t)MAXBUCK * 4);
    size_t o_sSD  = off; off = align256(off + (size_t)E * 8);
    size_t o_sId  = off; off = align256(off + (size_t)E * 4);
    size_t need_full = off;
    size_t need_fp16 = align256((size_t)n_nodes_elems * 2) * 2 + 4096;

    char* w = (char*)d_ws;
    int grid = (E + 255) / 256;

    if (ws_size >= need_full && nbuck <= MAXBUCK) {
        _Float16* EuH = (_Float16*)(w + o_EuH);
        _Float16* EvH = (_Float16*)(w + o_EvH);
        _Float16* EbH = (_Float16*)(w + o_EbH);
        unsigned* hist = (unsigned*)(w + o_hist);
        unsigned* cursor = (unsigned*)(w + o_cur);
        int2v* sSD = (int2v*)(w + o_sSD);
        int* sId = (int*)(w + o_sId);

        int n8 = n_nodes_elems / 8;
        cvt_f16_kernel<<<(n8 + 255) / 256, 256, 0, stream>>>(Eu, Ev, E_b, EuH, EvH, EbH, n8);
        (void)hipMemsetAsync(hist, 0, (size_t)MAXBUCK * 4, stream);
        hist_kernel<<<512, 256, 0, stream>>>(edge_index, E, nbuck, hist);
        scan_kernel<<<1, 1024, 0, stream>>>(hist, nbuck, cursor);
        int sblocks = (E + 512 * SEPB - 1) / (512 * SEPB);
        scatter_kernel<<<sblocks, 512, 0, stream>>>(edge_index, E, nbuck, cursor, sSD, sId);
        ptt_mfma_sorted_kernel<<<grid, 256, 0, stream>>>(EuH, EvH, sSD, sId, EbH, out, E);
    } else if (ws_size >= need_fp16) {
        _Float16* EuH = (_Float16*)w;
        _Float16* EvH = EuH + n_nodes_elems;
        _Float16* EbH = EvH + n_nodes_elems;
        int n8 = n_nodes_elems / 8;
        cvt_f16_kernel<<<(n8 + 255) / 256, 256, 0, stream>>>(Eu, Ev, E_b, EuH, EvH, EbH, n8);
        ptt_mfma_kernel<<<grid, 256, 0, stream>>>(EuH, EvH, edge_index, EbH, out, E);
    }
}

// Round 8
// 111.081 us; speedup vs baseline: 1.5468x; 1.5468x over previous
//
#include <hip/hip_runtime.h>

#define NB 32
#define DIM 64
#define TILE 2048          // original-edge range per block
#define NXCD 8

typedef _Float16 half8_t __attribute__((ext_vector_type(8)));
typedef float floatx4 __attribute__((ext_vector_type(4)));

// ---------------- prep: convert Eu/Ev/E_b (f32) -> fp16 tables in ws -------
__global__ __launch_bounds__(256) void cvt_f16_kernel(
    const float* __restrict__ Eu, const float* __restrict__ Ev,
    const float* __restrict__ E_b,
    _Float16* __restrict__ EuH, _Float16* __restrict__ EvH,
    _Float16* __restrict__ EbH, int n8)
{
    int i = blockIdx.x * blockDim.x + threadIdx.x;
    if (i < n8) {
        const float4* u4 = (const float4*)Eu + 2 * i;
        const float4* v4 = (const float4*)Ev + 2 * i;
        float4 a0 = u4[0], a1 = u4[1];
        float4 b0 = v4[0], b1 = v4[1];
        half8_t hu, hv;
        hu[0] = (_Float16)a0.x; hu[1] = (_Float16)a0.y; hu[2] = (_Float16)a0.z; hu[3] = (_Float16)a0.w;
        hu[4] = (_Float16)a1.x; hu[5] = (_Float16)a1.y; hu[6] = (_Float16)a1.z; hu[7] = (_Float16)a1.w;
        hv[0] = (_Float16)b0.x; hv[1] = (_Float16)b0.y; hv[2] = (_Float16)b0.z; hv[3] = (_Float16)b0.w;
        hv[4] = (_Float16)b1.x; hv[5] = (_Float16)b1.y; hv[6] = (_Float16)b1.z; hv[7] = (_Float16)b1.w;
        ((half8_t*)EuH)[i] = hu;
        ((half8_t*)EvH)[i] = hv;
    }
    if (blockIdx.x == 0) {
        int base = threadIdx.x * 8;
        if (base < NB * DIM) {
            const float4* b4 = (const float4*)(E_b + base);
            float4 x0 = b4[0], x1 = b4[1];
            half8_t h;
            h[0] = (_Float16)x0.x; h[1] = (_Float16)x0.y; h[2] = (_Float16)x0.z; h[3] = (_Float16)x0.w;
            h[4] = (_Float16)x1.x; h[5] = (_Float16)x1.y; h[6] = (_Float16)x1.z; h[7] = (_Float16)x1.w;
            *(half8_t*)(EbH + base) = h;
        }
    }
}

// ---------------- main: XCD-pinned dst-slice filter + MFMA ------------------
// Block b: XCD = b%8 (round-robin dispatch), tile = b>>3. Processes only the
// edges of its tile whose dst lies in node-slice [lo,hi) of its XCD. Each
// XCD's L2 then only caches a 1/8 v-slice (~800 KB fp16) -> v gathers L2-hot.
// Deterministic: every edge matches exactly one slice; out[id] written once.
__global__ __launch_bounds__(256, 4) void ptt_filter_kernel(
    const _Float16* __restrict__ EuH, const _Float16* __restrict__ EvH,
    const int* __restrict__ edge_index, const _Float16* __restrict__ EbH,
    float* __restrict__ out, int E, int n_nodes)
{
    __shared__ int qs[TILE], qd[TILE], qi[TILE];
    __shared__ int wsum[4];

    const int tid = threadIdx.x;
    const int lane = tid & 63;
    const int wave = tid >> 6;
    const int g = blockIdx.x & (NXCD - 1);
    const int e0 = (blockIdx.x >> 3) * TILE;

    const int lo = (int)((long long)g * n_nodes / NXCD);
    const int hi = (int)((long long)(g + 1) * n_nodes / NXCD);

    // ---- load 8 edges (strided, coalesced, nt) + match mask ----
    int src8[8], dst8[8];
    bool mk[8];
    int m8 = 0;
#pragma unroll
    for (int k = 0; k < 8; ++k) {
        int e = e0 + k * 256 + tid;
        int ec = e < E ? e : (E - 1);
        src8[k] = __builtin_nontemporal_load(edge_index + ec);
        dst8[k] = __builtin_nontemporal_load(edge_index + E + ec);
        mk[k] = (e < E) & (dst8[k] >= lo) & (dst8[k] < hi);
        m8 += mk[k] ? 1 : 0;
    }
    // ---- wave-inclusive scan of per-thread counts ----
    int pre = m8;
#pragma unroll
    for (int d = 1; d < 64; d <<= 1) {
        int n = __shfl_up(pre, d);
        if (lane >= d) pre += n;
    }
    if (lane == 63) wsum[wave] = pre;
    __syncthreads();
    int wbase = 0;
#pragma unroll
    for (int w = 0; w < 4; ++w) wbase += (w < wave) ? wsum[w] : 0;
    const int qc = wsum[0] + wsum[1] + wsum[2] + wsum[3];
    int off = wbase + pre - m8;
#pragma unroll
    for (int k = 0; k < 8; ++k) {
        if (mk[k]) {
            qs[off] = src8[k];
            qd[off] = dst8[k];
            qi[off] = e0 + k * 256 + tid;
            ++off;
        }
    }
    __syncthreads();
    if (qc == 0) return;

    const int j16 = lane & 15;
    const int gg = lane >> 4;

    // A fragments: E_b fp16 (L1-hot broadcast)
    half8_t Af[2][2];
#pragma unroll
    for (int mt = 0; mt < 2; ++mt)
#pragma unroll
        for (int ks = 0; ks < 2; ++ks)
            Af[mt][ks] = *(const half8_t*)(EbH + (mt * 16 + j16) * DIM + ks * 32 + gg * 8);

    // ---- split queue across 4 waves ----
    int per = (qc + 3) >> 2;
    per = (per + 15) & ~15;
    const int q0 = wave * per;
    const int q1 = (q0 + per < qc) ? (q0 + per) : qc;
    if (q0 >= qc) return;

    const char* ub = (const char*)EuH;
    const char* vb = (const char*)EvH;

    for (int base = q0; base < q1; base += 64) {
        int ss[4], dd[4], ii[4];
#pragma unroll
        for (int t = 0; t < 4; ++t) {
            int qx = base + t * 16 + j16;
            int qxc = qx < q1 ? qx : (q1 - 1);
            ss[t] = qs[qxc];
            dd[t] = qd[qxc];
            ii[t] = qi[qxc];
        }

        // issue v (L2-pinned slice) and u gathers, all before use
        half8_t u[4][2], v[4][2];
#pragma unroll
        for (int t = 0; t < 4; ++t) {
            unsigned sv = (unsigned)dd[t] * (DIM * 2u) + (unsigned)(gg * 16);
#pragma unroll
            for (int ks = 0; ks < 2; ++ks)
                v[t][ks] = *(const half8_t*)(vb + (sv + ks * 64u));
        }
#pragma unroll
        for (int t = 0; t < 4; ++t) {
            unsigned su = (unsigned)ss[t] * (DIM * 2u) + (unsigned)(gg * 16);
#pragma unroll
            for (int ks = 0; ks < 2; ++ks)
                u[t][ks] = *(const half8_t*)(ub + (su + ks * 64u));
        }

        floatx4 acc[4][2];
#pragma unroll
        for (int t = 0; t < 4; ++t) {
            acc[t][0] = (floatx4){0.f, 0.f, 0.f, 0.f};
            acc[t][1] = (floatx4){0.f, 0.f, 0.f, 0.f};
        }
#pragma unroll
        for (int t = 0; t < 4; ++t)
#pragma unroll
            for (int ks = 0; ks < 2; ++ks) {
                half8_t r = u[t][ks] * v[t][ks];  // v_pk_mul_f16
                acc[t][0] = __builtin_amdgcn_mfma_f32_16x16x32_f16(Af[0][ks], r, acc[t][0], 0, 0, 0);
                acc[t][1] = __builtin_amdgcn_mfma_f32_16x16x32_f16(Af[1][ks], r, acc[t][1], 0, 0, 0);
            }

        // epilogue: softmax-weighted logit mean + sigmoid (no max-sub, |logit|<~8)
#pragma unroll
        for (int t = 0; t < 4; ++t) {
            float s1 = 0.f, s2 = 0.f;
#pragma unroll
            for (int mt = 0; mt < 2; ++mt)
#pragma unroll
                for (int q = 0; q < 4; ++q) {
                    float a = acc[t][mt][q];
                    float p = __expf(a);
                    s1 += p;
                    s2 = fmaf(p, a, s2);
                }
            s1 += __shfl_xor(s1, 16);
            s2 += __shfl_xor(s2, 16);
            s1 += __shfl_xor(s1, 32);
            s2 += __shfl_xor(s2, 32);
            float x = __fdividef(s2, s1);
            float score = __fdividef(1.0f, 1.0f + __expf(-x));
            if (lane < 16 && (base + t * 16 + j16) < q1)
                __builtin_nontemporal_store(score, out + ii[t]);
        }
    }
}

// ---------------- fallback: unsorted fp16 path (round-5 proven) ------------
__global__ __launch_bounds__(256, 4) void ptt_mfma_kernel(
    const _Float16* __restrict__ EuH, const _Float16* __restrict__ EvH,
    const int* __restrict__ edge_index,
    const _Float16* __restrict__ EbH,
    float* __restrict__ out, int E)
{
    const int lane = threadIdx.x & 63;
    const int wave = threadIdx.x >> 6;
    const int j16 = lane & 15;
    const int g = lane >> 4;
    const int eb = (blockIdx.x * 4 + wave) * 64;

    int isrc[4], idst[4];
#pragma unroll
    for (int t = 0; t < 4; ++t) {
        int e = eb + t * 16 + j16;
        int ec = e < E ? e : (E - 1);
        isrc[t] = __builtin_nontemporal_load(edge_index + ec);
        idst[t] = __builtin_nontemporal_load(edge_index + E + ec);
    }

    half8_t Af[2][2];
#pragma unroll
    for (int mt = 0; mt < 2; ++mt)
#pragma unroll
        for (int ks = 0; ks < 2; ++ks)
            Af[mt][ks] = *(const half8_t*)(EbH + (mt * 16 + j16) * DIM + ks * 32 + g * 8);

    const char* ub = (const char*)EuH;
    const char* vb = (const char*)EvH;
    half8_t u[4][2], v[4][2];
#pragma unroll
    for (int t = 0; t < 4; ++t) {
        unsigned su = (unsigned)isrc[t] * (DIM * 2u) + (unsigned)(g * 16);
        unsigned sv = (unsigned)idst[t] * (DIM * 2u) + (unsigned)(g * 16);
#pragma unroll
        for (int ks = 0; ks < 2; ++ks) {
            u[t][ks] = *(const half8_t*)(ub + (su + ks * 64u));
            v[t][ks] = *(const half8_t*)(vb + (sv + ks * 64u));
        }
    }

    floatx4 acc[4][2];
#pragma unroll
    for (int t = 0; t < 4; ++t) {
        acc[t][0] = (floatx4){0.f, 0.f, 0.f, 0.f};
        acc[t][1] = (floatx4){0.f, 0.f, 0.f, 0.f};
    }
#pragma unroll
    for (int t = 0; t < 4; ++t)
#pragma unroll
        for (int ks = 0; ks < 2; ++ks) {
            half8_t r = u[t][ks] * v[t][ks];
            acc[t][0] = __builtin_amdgcn_mfma_f32_16x16x32_f16(Af[0][ks], r, acc[t][0], 0, 0, 0);
            acc[t][1] = __builtin_amdgcn_mfma_f32_16x16x32_f16(Af[1][ks], r, acc[t][1], 0, 0, 0);
        }

#pragma unroll
    for (int t = 0; t < 4; ++t) {
        float s1 = 0.f, s2 = 0.f;
#pragma unroll
        for (int mt = 0; mt < 2; ++mt)
#pragma unroll
            for (int q = 0; q < 4; ++q) {
                float a = acc[t][mt][q];
                float p = __expf(a);
                s1 += p;
                s2 = fmaf(p, a, s2);
            }
        s1 += __shfl_xor(s1, 16);
        s2 += __shfl_xor(s2, 16);
        s1 += __shfl_xor(s1, 32);
        s2 += __shfl_xor(s2, 32);
        float x = __fdividef(s2, s1);
        float score = __fdividef(1.0f, 1.0f + __expf(-x));
        if (lane < 16) {
            int eo = eb + t * 16 + j16;
            if (eo < E) __builtin_nontemporal_store(score, out + eo);
        }
    }
}

static inline size_t align256(size_t x) { return (x + 255) & ~(size_t)255; }

extern "C" void kernel_launch(void* const* d_in, const int* in_sizes, int n_in,
                              void* d_out, int out_size, void* d_ws, size_t ws_size,
                              hipStream_t stream) {
    const float* Eu = (const float*)d_in[0];
    const float* Ev = (const float*)d_in[1];
    const int* edge_index = (const int*)d_in[2];  // harness delivers int32
    const float* E_b = (const float*)d_in[3];
    float* out = (float*)d_out;

    int n_nodes_elems = in_sizes[0];  // 50000*64
    int n_nodes = n_nodes_elems / DIM;
    int E = in_sizes[2] / 2;
    size_t need = align256((size_t)n_nodes_elems * 2) * 2 +
                  align256((size_t)NB * DIM * 2);

    if (ws_size < need) return;  // ws has always been sufficient

    char* w = (char*)d_ws;
    _Float16* EuH = (_Float16*)w;
    _Float16* EvH = (_Float16*)(w + align256((size_t)n_nodes_elems * 2));
    _Float16* EbH = (_Float16*)(w + align256((size_t)n_nodes_elems * 2) * 2);

    int n8 = n_nodes_elems / 8;
    cvt_f16_kernel<<<(n8 + 255) / 256, 256, 0, stream>>>(Eu, Ev, E_b, EuH, EvH, EbH, n8);

    int ntiles = (E + TILE - 1) / TILE;
    int grid = ntiles * NXCD;
    ptt_filter_kernel<<<grid, 256, 0, stream>>>(EuH, EvH, edge_index, EbH, out, E, n_nodes);
}

// Round 9
// 85.246 us; speedup vs baseline: 2.0156x; 1.3031x over previous
//
#include <hip/hip_runtime.h>

#define NB 32
#define DIM 64

typedef _Float16 half8_t __attribute__((ext_vector_type(8)));
typedef float floatx4 __attribute__((ext_vector_type(4)));

// ---------------- prep: convert Eu/Ev/E_b (f32) -> fp16 tables in ws -------
__global__ __launch_bounds__(256) void cvt_f16_kernel(
    const float* __restrict__ Eu, const float* __restrict__ Ev,
    const float* __restrict__ E_b,
    _Float16* __restrict__ EuH, _Float16* __restrict__ EvH,
    _Float16* __restrict__ EbH, int n8)
{
    int i = blockIdx.x * blockDim.x + threadIdx.x;
    if (i < n8) {
        const float4* u4 = (const float4*)Eu + 2 * i;
        const float4* v4 = (const float4*)Ev + 2 * i;
        float4 a0 = u4[0], a1 = u4[1];
        float4 b0 = v4[0], b1 = v4[1];
        half8_t hu, hv;
        hu[0] = (_Float16)a0.x; hu[1] = (_Float16)a0.y; hu[2] = (_Float16)a0.z; hu[3] = (_Float16)a0.w;
        hu[4] = (_Float16)a1.x; hu[5] = (_Float16)a1.y; hu[6] = (_Float16)a1.z; hu[7] = (_Float16)a1.w;
        hv[0] = (_Float16)b0.x; hv[1] = (_Float16)b0.y; hv[2] = (_Float16)b0.z; hv[3] = (_Float16)b0.w;
        hv[4] = (_Float16)b1.x; hv[5] = (_Float16)b1.y; hv[6] = (_Float16)b1.z; hv[7] = (_Float16)b1.w;
        ((half8_t*)EuH)[i] = hu;
        ((half8_t*)EvH)[i] = hv;
    }
    if (blockIdx.x == 0) {
        int base = threadIdx.x * 8;
        if (base < NB * DIM) {
            const float4* b4 = (const float4*)(E_b + base);
            float4 x0 = b4[0], x1 = b4[1];
            half8_t h;
            h[0] = (_Float16)x0.x; h[1] = (_Float16)x0.y; h[2] = (_Float16)x0.z; h[3] = (_Float16)x0.w;
            h[4] = (_Float16)x1.x; h[5] = (_Float16)x1.y; h[6] = (_Float16)x1.z; h[7] = (_Float16)x1.w;
            *(half8_t*)(EbH + base) = h;
        }
    }
}

// ---------------- main: per-wave 64 edges, logits transposed ----------------
// acc = mfma(A = E_b rows, B = r^T):
//   D-frag: col = lane&15 = edge, row = (lane>>4)*4 + reg = b (within mt tile)
// ALL 16 table gathers are issued before a sched_barrier(0) fence, so the
// scheduler cannot re-serialize them to save VGPRs: 16 vmem instructions
// (256 cache lines per wave) stay in flight; the compiler's counted vmcnt
// then drains progressively as t=0..3 tiles are consumed.
__global__ __launch_bounds__(256, 4) void ptt_mfma_kernel(
    const _Float16* __restrict__ EuH, const _Float16* __restrict__ EvH,
    const int* __restrict__ edge_index,
    const _Float16* __restrict__ EbH,
    float* __restrict__ out, int E)
{
    const int lane = threadIdx.x & 63;
    const int wave = threadIdx.x >> 6;
    const int j16 = lane & 15;
    const int g = lane >> 4;
    const int eb = (blockIdx.x * 4 + wave) * 64;

    // Edge indices (coalesced, streamed once -> nontemporal).
    int isrc[4], idst[4];
#pragma unroll
    for (int t = 0; t < 4; ++t) {
        int e = eb + t * 16 + j16;
        int ec = e < E ? e : (E - 1);
        isrc[t] = __builtin_nontemporal_load(edge_index + ec);
        idst[t] = __builtin_nontemporal_load(edge_index + E + ec);
    }

    // A fragments: E_b fp16 (L1-hot, broadcast across waves).
    half8_t Af[2][2];
#pragma unroll
    for (int mt = 0; mt < 2; ++mt)
#pragma unroll
        for (int ks = 0; ks < 2; ++ks)
            Af[mt][ks] = *(const half8_t*)(EbH + (mt * 16 + j16) * DIM + ks * 32 + g * 8);

    // ---- issue ALL 16 gathers, t-major so the drain is progressive ----
    const char* ub = (const char*)EuH;
    const char* vb = (const char*)EvH;
    half8_t u[4][2], v[4][2];
#pragma unroll
    for (int t = 0; t < 4; ++t) {
        unsigned su = (unsigned)isrc[t] * (DIM * 2u) + (unsigned)(g * 16);
        unsigned sv = (unsigned)idst[t] * (DIM * 2u) + (unsigned)(g * 16);
#pragma unroll
        for (int ks = 0; ks < 2; ++ks) {
            u[t][ks] = *(const half8_t*)(ub + (su + ks * 64u));
            v[t][ks] = *(const half8_t*)(vb + (sv + ks * 64u));
        }
    }
    // Fence: nothing below may be scheduled above this point, so all 16
    // loads are issued back-to-back and their results stay register-live.
    __builtin_amdgcn_sched_barrier(0);

    floatx4 acc[4][2];
#pragma unroll
    for (int t = 0; t < 4; ++t) {
        acc[t][0] = (floatx4){0.f, 0.f, 0.f, 0.f};
        acc[t][1] = (floatx4){0.f, 0.f, 0.f, 0.f};
    }

#pragma unroll
    for (int t = 0; t < 4; ++t)
#pragma unroll
        for (int ks = 0; ks < 2; ++ks) {
            half8_t r = u[t][ks] * v[t][ks];  // v_pk_mul_f16
            acc[t][0] = __builtin_amdgcn_mfma_f32_16x16x32_f16(Af[0][ks], r, acc[t][0], 0, 0, 0);
            acc[t][1] = __builtin_amdgcn_mfma_f32_16x16x32_f16(Af[1][ks], r, acc[t][1], 0, 0, 0);
        }

    // Epilogue: softmax-weighted logit mean + sigmoid (no max-sub, |logit|<~8).
#pragma unroll
    for (int t = 0; t < 4; ++t) {
        float s1 = 0.f, s2 = 0.f;
#pragma unroll
        for (int mt = 0; mt < 2; ++mt)
#pragma unroll
            for (int q = 0; q < 4; ++q) {
                float a = acc[t][mt][q];
                float p = __expf(a);
                s1 += p;
                s2 = fmaf(p, a, s2);
            }
        s1 += __shfl_xor(s1, 16);
        s2 += __shfl_xor(s2, 16);
        s1 += __shfl_xor(s1, 32);
        s2 += __shfl_xor(s2, 32);
        float x = __fdividef(s2, s1);
        float score = __fdividef(1.0f, 1.0f + __expf(-x));
        if (lane < 16) {
            int eo = eb + t * 16 + j16;
            if (eo < E) __builtin_nontemporal_store(score, out + eo);
        }
    }
}

static inline size_t align256(size_t x) { return (x + 255) & ~(size_t)255; }

extern "C" void kernel_launch(void* const* d_in, const int* in_sizes, int n_in,
                              void* d_out, int out_size, void* d_ws, size_t ws_size,
                              hipStream_t stream) {
    const float* Eu = (const float*)d_in[0];
    const float* Ev = (const float*)d_in[1];
    const int* edge_index = (const int*)d_in[2];  // harness delivers int32
    const float* E_b = (const float*)d_in[3];
    float* out = (float*)d_out;

    int n_nodes_elems = in_sizes[0];  // 50000*64
    int E = in_sizes[2] / 2;
    size_t need = align256((size_t)n_nodes_elems * 2) * 2 +
                  align256((size_t)NB * DIM * 2);
    if (ws_size < need) return;  // ws has always been sufficient

    char* w = (char*)d_ws;
    _Float16* EuH = (_Float16*)w;
    _Float16* EvH = (_Float16*)(w + align256((size_t)n_nodes_elems * 2));
    _Float16* EbH = (_Float16*)(w + align256((size_t)n_nodes_elems * 2) * 2);

    int n8 = n_nodes_elems / 8;
    cvt_f16_kernel<<<(n8 + 255) / 256, 256, 0, stream>>>(Eu, Ev, E_b, EuH, EvH, EbH, n8);

    int grid = (E + 255) / 256;
    ptt_mfma_kernel<<<grid, 256, 0, stream>>>(EuH, EvH, edge_index, EbH, out, E);
}